// Round 5
// baseline (414.819 us; speedup 1.0000x reference)
//
#include <hip/hip_runtime.h>
#include <hip/hip_bf16.h>

#define N_NODES 50000
#define N_EDGES 800000
#define HID 64
#define N_GRAPHS 64
#define N_CLASSES 10
#define BN_EPS 1e-5f

typedef unsigned int uint;

__device__ __forceinline__ float blo(uint u) { return __uint_as_float(u << 16); }
__device__ __forceinline__ float bhi(uint u) { return __uint_as_float(u & 0xffff0000u); }
__device__ __forceinline__ unsigned short f2b(float f) {
  __hip_bfloat16 h = __float2bfloat16(f);
  return *reinterpret_cast<unsigned short*>(&h);
}

// ---------------- CSR build ----------------

__global__ void k_count_deg(const int* __restrict__ dst, int* __restrict__ deg) {
  int e = blockIdx.x * blockDim.x + threadIdx.x;
  if (e < N_EDGES) atomicAdd(&deg[dst[e]], 1);
}

__global__ void k_scan_block(const int* __restrict__ deg, int* __restrict__ rowp,
                             int* __restrict__ bsum, float* __restrict__ dis) {
  __shared__ int s[256];
  int tid = threadIdx.x;
  int i = blockIdx.x * 256 + tid;
  int v = (i < N_NODES) ? deg[i] : 0;
  if (i < N_NODES) dis[i] = rsqrtf((float)v + 1.0f);
  s[tid] = v;
  __syncthreads();
  for (int off = 1; off < 256; off <<= 1) {
    int t = (tid >= off) ? s[tid - off] : 0;
    __syncthreads();
    s[tid] += t;
    __syncthreads();
  }
  if (i < N_NODES) rowp[i] = s[tid] - v;
  if (tid == 255) bsum[blockIdx.x] = s[255];
}

__global__ void k_scan_partials(int* __restrict__ bsum, int nb) {
  __shared__ int s[256];
  int tid = threadIdx.x;
  int v = (tid < nb) ? bsum[tid] : 0;
  s[tid] = v;
  __syncthreads();
  for (int off = 1; off < 256; off <<= 1) {
    int t = (tid >= off) ? s[tid - off] : 0;
    __syncthreads();
    s[tid] += t;
    __syncthreads();
  }
  if (tid < nb) bsum[tid] = s[tid] - v;
}

__global__ void k_scan_finish(int* __restrict__ rowp, const int* __restrict__ bsum,
                              int* __restrict__ cursor) {
  int i = blockIdx.x * blockDim.x + threadIdx.x;
  if (i < N_NODES) {
    int v = rowp[i] + bsum[i >> 8];
    rowp[i] = v;
    cursor[i] = v;
  }
  if (i == 0) rowp[N_NODES] = N_EDGES;
}

// pack {src:16 | bf16(coef):16} per edge, grouped by dst
__global__ void k_fill_edges(const int* __restrict__ ei, const float* __restrict__ dis,
                             int* __restrict__ cursor, uint* __restrict__ edata) {
  int e = blockIdx.x * blockDim.x + threadIdx.x;
  if (e < N_EDGES) {
    int s = ei[e];
    int d = ei[N_EDGES + e];
    int pos = atomicAdd(&cursor[d], 1);
    edata[pos] = ((uint)s << 16) | f2b(dis[s] * dis[d]);
  }
}

// ---------------- per-layer ----------------

// out16[n][j] = bf16( sum_k bnrelu(in[n][k]) * W[k][j] )
template <bool IN_BF16>
__global__ __launch_bounds__(256) void k_gemm(const void* __restrict__ in,
                                              const float* __restrict__ W,
                                              __hip_bfloat16* __restrict__ out,
                                              float* __restrict__ stats_zero,
                                              const float* __restrict__ stats_in,
                                              const float* __restrict__ gamma,
                                              const float* __restrict__ beta) {
  __shared__ float Al[4][64];
  int tid = threadIdx.x;
  int wid = tid >> 6, f = tid & 63;
  if (blockIdx.x == 0) {
    for (int i = tid; i < 1024; i += 256) stats_zero[i] = 0.0f;
  }
  float Wreg[64];
#pragma unroll
  for (int k = 0; k < 64; ++k) Wreg[k] = W[k * 64 + f];
  float sc = 1.f, sh = 0.f;
  if (stats_in) {
    float s = 0.f, q = 0.f;
#pragma unroll
    for (int c = 0; c < 8; ++c) {
      s += stats_in[c * 128 + f];
      q += stats_in[c * 128 + 64 + f];
    }
    float mu = s * (1.0f / N_NODES);
    float var = q * (1.0f / N_NODES) - mu * mu;
    sc = gamma[f] * rsqrtf(var + BN_EPS);
    sh = beta[f] - mu * sc;
  }
  for (int n = blockIdx.x * 4 + wid; n < N_NODES; n += gridDim.x * 4) {
    float av;
    if (IN_BF16)
      av = __bfloat162float(((const __hip_bfloat16*)in)[(n << 6) + f]);
    else
      av = ((const float*)in)[(n << 6) + f];
    if (stats_in) {
      av = fmaf(av, sc, sh);
      av = av > 0.f ? av : 0.f;
    }
    Al[wid][f] = av;  // same-wave LDS: ordered, no barrier
    float acc = 0.f;
    const float4* arow = (const float4*)Al[wid];
#pragma unroll
    for (int k4 = 0; k4 < 16; ++k4) {
      float4 a = arow[k4];
      acc = fmaf(a.x, Wreg[k4 * 4 + 0], acc);
      acc = fmaf(a.y, Wreg[k4 * 4 + 1], acc);
      acc = fmaf(a.z, Wreg[k4 * 4 + 2], acc);
      acc = fmaf(a.w, Wreg[k4 * 4 + 3], acc);
    }
    out[(n << 6) + f] = __float2bfloat16(acc);
  }
}

// U gather instructions, 8 edges each; edge record pulled from reg via shuffle
template <int U>
__device__ __forceinline__ void gathN(uint er, int jbase, const uint4* __restrict__ hw4,
                                      int l8, int g, float acc[8]) {
  uint e[U];
  uint4 hv[U];
  float wv[U];
#pragma unroll
  for (int u = 0; u < U; ++u) e[u] = __shfl(er, jbase + u * 8 + g, 64);
#pragma unroll
  for (int u = 0; u < U; ++u) {
    wv[u] = blo(e[u]);
    hv[u] = hw4[(e[u] >> 16) * 8 + l8];
  }
#pragma unroll
  for (int u = 0; u < U; ++u) {
    acc[0] = fmaf(blo(hv[u].x), wv[u], acc[0]);
    acc[1] = fmaf(bhi(hv[u].x), wv[u], acc[1]);
    acc[2] = fmaf(blo(hv[u].y), wv[u], acc[2]);
    acc[3] = fmaf(bhi(hv[u].y), wv[u], acc[3]);
    acc[4] = fmaf(blo(hv[u].z), wv[u], acc[4]);
    acc[5] = fmaf(bhi(hv[u].z), wv[u], acc[5]);
    acc[6] = fmaf(blo(hv[u].w), wv[u], acc[6]);
    acc[7] = fmaf(bhi(hv[u].w), wv[u], acc[7]);
  }
}

__device__ __forceinline__ void do_batch(uint er, int c, const uint4* __restrict__ hw4,
                                         int l8, int g, float acc[8]) {
  if (c > 32) {
    gathN<4>(er, 0, hw4, l8, g, acc);
    gathN<4>(er, 32, hw4, l8, g, acc);
  } else if (c > 16) {
    gathN<4>(er, 0, hw4, l8, g, acc);
  } else if (c > 8) {
    gathN<2>(er, 0, hw4, l8, g, acc);
  } else {
    gathN<1>(er, 0, hw4, l8, g, acc);
  }
}

// gather-aggregate + self-loop + bias; bf16 rows (128B); reg-shuffled edges
__global__ __launch_bounds__(256, 8) void k_agg(const __hip_bfloat16* __restrict__ hW,
                                                const float* __restrict__ dis,
                                                const int* __restrict__ rowp,
                                                const uint* __restrict__ edata,
                                                const float* __restrict__ bias,
                                                __hip_bfloat16* __restrict__ act,
                                                float* __restrict__ stats) {
  __shared__ float ssum[4][64], ssq[4][64];
  int tid = threadIdx.x;
  int wid = tid >> 6, lane = tid & 63;
  int g = lane >> 3, l8 = lane & 7;
  ssum[wid][lane] = 0.f;  // same-wave init, no barrier needed before RMW below
  ssq[wid][lane] = 0.f;
  const uint4* hw4 = (const uint4*)hW;
  int stride = gridDim.x * 4;
  int n = blockIdx.x * 4 + wid;
  int p0 = 0, p1 = 0, np0 = 0, np1 = 0;
  uint er = 0;
  if (n < N_NODES) {
    p0 = rowp[n];
    p1 = rowp[n + 1];
    int n1 = n + stride;
    if (n1 < N_NODES) {
      np0 = rowp[n1];
      np1 = rowp[n1 + 1];
    }
    er = (p0 + lane < p1) ? edata[p0 + lane] : 0u;
  }
  for (; n < N_NODES; n += stride) {
    uint4 hself = hw4[n * 8 + l8];  // early, independent
    float dn = dis[n];
    // prefetch rowp two ahead, edata one ahead
    int n2 = n + 2 * stride;
    int pp0 = 0, pp1 = 0;
    if (n2 < N_NODES) {
      pp0 = rowp[n2];
      pp1 = rowp[n2 + 1];
    }
    uint ner = 0;
    if (n + stride < N_NODES) ner = (np0 + lane < np1) ? edata[np0 + lane] : 0u;

    float acc[8] = {0, 0, 0, 0, 0, 0, 0, 0};
    int cnt = p1 - p0;
    do_batch(er, cnt > 64 ? 64 : cnt, hw4, l8, g, acc);
    for (int pb = p0 + 64; pb < p1; pb += 64) {  // rare (deg > 64)
      uint er2 = (pb + lane < p1) ? edata[pb + lane] : 0u;
      int c = p1 - pb;
      do_batch(er2, c > 64 ? 64 : c, hw4, l8, g, acc);
    }
#pragma unroll
    for (int off = 8; off < 64; off <<= 1) {
#pragma unroll
      for (int i = 0; i < 8; ++i) acc[i] += __shfl_xor(acc[i], off, 64);
    }
    if (g == 0) {
      float dn2 = dn * dn;
      float pre[8];
      pre[0] = fmaf(blo(hself.x), dn2, acc[0]);
      pre[1] = fmaf(bhi(hself.x), dn2, acc[1]);
      pre[2] = fmaf(blo(hself.y), dn2, acc[2]);
      pre[3] = fmaf(bhi(hself.y), dn2, acc[3]);
      pre[4] = fmaf(blo(hself.z), dn2, acc[4]);
      pre[5] = fmaf(bhi(hself.z), dn2, acc[5]);
      pre[6] = fmaf(blo(hself.w), dn2, acc[6]);
      pre[7] = fmaf(bhi(hself.w), dn2, acc[7]);
      const float4* b4 = (const float4*)bias;
      float4 bA = b4[l8 * 2], bB = b4[l8 * 2 + 1];
      pre[0] += bA.x; pre[1] += bA.y; pre[2] += bA.z; pre[3] += bA.w;
      pre[4] += bB.x; pre[5] += bB.y; pre[6] += bB.z; pre[7] += bB.w;
      uint4 st;
      st.x = (uint)f2b(pre[0]) | ((uint)f2b(pre[1]) << 16);
      st.y = (uint)f2b(pre[2]) | ((uint)f2b(pre[3]) << 16);
      st.z = (uint)f2b(pre[4]) | ((uint)f2b(pre[5]) << 16);
      st.w = (uint)f2b(pre[6]) | ((uint)f2b(pre[7]) << 16);
      ((uint4*)act)[n * 8 + l8] = st;
      float* su = &ssum[wid][l8 * 8];
      float* sq = &ssq[wid][l8 * 8];
#pragma unroll
      for (int i = 0; i < 8; ++i) {  // LDS RMW: keeps stats out of registers
        su[i] += pre[i];
        sq[i] = fmaf(pre[i], pre[i], sq[i]);
      }
    }
    p0 = np0; p1 = np1; np0 = pp0; np1 = pp1; er = ner;
  }
  __syncthreads();
  if (tid < 64) {
    float s4 = ssum[0][tid] + ssum[1][tid] + ssum[2][tid] + ssum[3][tid];
    float q4 = ssq[0][tid] + ssq[1][tid] + ssq[2][tid] + ssq[3][tid];
    float* sl = stats + (blockIdx.x & 7) * 128;  // 8-way de-contended
    atomicAdd(&sl[tid], s4);
    atomicAdd(&sl[64 + tid], q4);
  }
}

// ---------------- pool + MLP ----------------

__global__ __launch_bounds__(256) void k_pool(const __hip_bfloat16* __restrict__ act,
                                              const float* __restrict__ stats_in,
                                              const float* __restrict__ gamma,
                                              const float* __restrict__ beta,
                                              float* __restrict__ pooled) {
  int g = blockIdx.x;
  int tid = threadIdx.x;
  int l16 = tid & 15;   // feats 4*l16 .. 4*l16+3
  int r = tid >> 4;     // 16 row-slices
  float sc[4], sh[4];
#pragma unroll
  for (int i = 0; i < 4; ++i) {
    int f = l16 * 4 + i;
    float s = 0.f, q = 0.f;
#pragma unroll
    for (int c = 0; c < 8; ++c) {
      s += stats_in[c * 128 + f];
      q += stats_in[c * 128 + 64 + f];
    }
    float mu = s * (1.0f / N_NODES);
    float var = q * (1.0f / N_NODES) - mu * mu;
    sc[i] = gamma[f] * rsqrtf(var + BN_EPS);
    sh[i] = beta[f] - mu * sc[i];
  }
  int gs = g * N_NODES;
  int start = (gs + 63) >> 6;
  int end = (gs + N_NODES + 63) >> 6;
  float m[4] = {0.f, 0.f, 0.f, 0.f};  // post-ReLU >= 0
  const uint2* a2 = (const uint2*)act;
  for (int n = start + r; n < end; n += 16) {
    uint2 v = a2[n * 16 + l16];
    float a0 = blo(v.x), a1 = bhi(v.x), a2v = blo(v.y), a3 = bhi(v.y);
    float t0 = fmaf(a0, sc[0], sh[0]);
    float t1 = fmaf(a1, sc[1], sh[1]);
    float t2 = fmaf(a2v, sc[2], sh[2]);
    float t3 = fmaf(a3, sc[3], sh[3]);
    m[0] = fmaxf(m[0], t0); m[1] = fmaxf(m[1], t1);
    m[2] = fmaxf(m[2], t2); m[3] = fmaxf(m[3], t3);
  }
  __shared__ float sm[16][64];
#pragma unroll
  for (int i = 0; i < 4; ++i) sm[r][l16 * 4 + i] = m[i];
  __syncthreads();
  if (tid < 64) {
    float mm = sm[0][tid];
#pragma unroll
    for (int rr = 1; rr < 16; ++rr) mm = fmaxf(mm, sm[rr][tid]);
    pooled[g * 64 + tid] = mm;  // ReLU(x) max over rows, values clamped >= 0
  }
}

__global__ __launch_bounds__(256) void k_final(const float* __restrict__ pooled,
                                               const float* __restrict__ w1,
                                               const float* __restrict__ b1,
                                               const float* __restrict__ w2,
                                               const float* __restrict__ b2,
                                               float* __restrict__ out) {
  __shared__ float P[64 * 64];
  __shared__ float Hd[64 * 64];
  int tid = threadIdx.x;
  for (int i = tid; i < 4096; i += 256) P[i] = pooled[i];
  __syncthreads();
  for (int i = tid; i < 4096; i += 256) {
    int g = i >> 6, j = i & 63;
    float acc = b1[j];
#pragma unroll
    for (int k = 0; k < 64; ++k) acc = fmaf(P[g * 64 + k], w1[k * 64 + j], acc);
    Hd[i] = acc > 0.f ? acc : 0.f;
  }
  __syncthreads();
  for (int i = tid; i < 640; i += 256) {
    int g = i / 10, c = i % 10;
    float acc = b2[c];
#pragma unroll
    for (int k = 0; k < 64; ++k) acc = fmaf(Hd[g * 64 + k], w2[k * 10 + c], acc);
    out[i] = acc;
  }
}

// ---------------- launch ----------------

extern "C" void kernel_launch(void* const* d_in, const int* in_sizes, int n_in,
                              void* d_out, int out_size, void* d_ws, size_t ws_size,
                              hipStream_t stream) {
  const float* x = (const float*)d_in[0];
  const int* ei = (const int*)d_in[1];
  const float* W1 = (const float*)d_in[3];
  const float* b1 = (const float*)d_in[4];
  const float* W2 = (const float*)d_in[5];
  const float* b2 = (const float*)d_in[6];
  const float* W3 = (const float*)d_in[7];
  const float* b3 = (const float*)d_in[8];
  const float* gamma = (const float*)d_in[9];
  const float* beta = (const float*)d_in[10];
  const float* l1w = (const float*)d_in[11];
  const float* l1b = (const float*)d_in[12];
  const float* l2w = (const float*)d_in[13];
  const float* l2b = (const float*)d_in[14];
  float* out = (float*)d_out;

  char* ws = (char*)d_ws;
  size_t off = 0;
  auto alloc = [&](size_t bytes) {
    void* p = ws + off;
    off = (off + bytes + 255) & ~(size_t)255;
    return p;
  };
  int* deg = (int*)alloc(N_NODES * 4);
  int* rowp = (int*)alloc((N_NODES + 1) * 4);
  int* cursor = (int*)alloc(N_NODES * 4);
  int* bsum = (int*)alloc(256 * 4);
  uint* edata = (uint*)alloc((size_t)N_EDGES * 4);
  float* dis = (float*)alloc(N_NODES * 4);
  __hip_bfloat16* hW = (__hip_bfloat16*)alloc((size_t)N_NODES * 64 * 2);
  __hip_bfloat16* act = (__hip_bfloat16*)alloc((size_t)N_NODES * 64 * 2);
  float* statsL0 = (float*)alloc(1024 * 4);
  float* statsL1 = (float*)alloc(1024 * 4);
  float* statsL2 = (float*)alloc(1024 * 4);
  float* pooled = (float*)alloc(4096 * 4);

  int nsb = (N_NODES + 255) / 256;  // 196

  hipMemsetAsync(deg, 0, N_NODES * 4, stream);
  k_count_deg<<<(N_EDGES + 255) / 256, 256, 0, stream>>>(ei + N_EDGES, deg);
  k_scan_block<<<nsb, 256, 0, stream>>>(deg, rowp, bsum, dis);
  k_scan_partials<<<1, 256, 0, stream>>>(bsum, nsb);
  k_scan_finish<<<nsb, 256, 0, stream>>>(rowp, bsum, cursor);
  k_fill_edges<<<(N_EDGES + 255) / 256, 256, 0, stream>>>(ei, dis, cursor, edata);

  // layer 1
  k_gemm<false><<<2048, 256, 0, stream>>>(x, W1, hW, statsL0, nullptr, gamma, beta);
  k_agg<<<2048, 256, 0, stream>>>(hW, dis, rowp, edata, b1, act, statsL0);
  // layer 2
  k_gemm<true><<<2048, 256, 0, stream>>>(act, W2, hW, statsL1, statsL0, gamma, beta);
  k_agg<<<2048, 256, 0, stream>>>(hW, dis, rowp, edata, b2, act, statsL1);
  // layer 3
  k_gemm<true><<<2048, 256, 0, stream>>>(act, W3, hW, statsL2, statsL1, gamma, beta);
  k_agg<<<2048, 256, 0, stream>>>(hW, dis, rowp, edata, b3, act, statsL2);

  k_pool<<<N_GRAPHS, 256, 0, stream>>>(act, statsL2, gamma, beta, pooled);
  k_final<<<1, 256, 0, stream>>>(pooled, l1w, l1b, l2w, l2b, out);
}

// Round 6
// 261.428 us; speedup vs baseline: 1.5867x; 1.5867x over previous
//
#include <hip/hip_runtime.h>
#include <hip/hip_bf16.h>

#define N_NODES 50000
#define N_EDGES 800000
#define HID 64
#define N_GRAPHS 64
#define N_CLASSES 10
#define BN_EPS 1e-5f

typedef unsigned int uint;

__device__ __forceinline__ float blo(uint u) { return __uint_as_float(u << 16); }
__device__ __forceinline__ float bhi(uint u) { return __uint_as_float(u & 0xffff0000u); }
__device__ __forceinline__ unsigned short f2b(float f) {
  __hip_bfloat16 h = __float2bfloat16(f);
  return *reinterpret_cast<unsigned short*>(&h);
}

// ---------------- CSR build ----------------

__global__ void k_count_deg(const int* __restrict__ dst, int* __restrict__ deg) {
  int e = blockIdx.x * blockDim.x + threadIdx.x;
  if (e < N_EDGES) atomicAdd(&deg[dst[e]], 1);
}

__global__ void k_scan_block(const int* __restrict__ deg, int* __restrict__ rowp,
                             int* __restrict__ bsum, float* __restrict__ dis) {
  __shared__ int s[256];
  int tid = threadIdx.x;
  int i = blockIdx.x * 256 + tid;
  int v = (i < N_NODES) ? deg[i] : 0;
  if (i < N_NODES) dis[i] = rsqrtf((float)v + 1.0f);
  s[tid] = v;
  __syncthreads();
  for (int off = 1; off < 256; off <<= 1) {
    int t = (tid >= off) ? s[tid - off] : 0;
    __syncthreads();
    s[tid] += t;
    __syncthreads();
  }
  if (i < N_NODES) rowp[i] = s[tid] - v;
  if (tid == 255) bsum[blockIdx.x] = s[255];
}

__global__ void k_scan_partials(int* __restrict__ bsum, int nb) {
  __shared__ int s[256];
  int tid = threadIdx.x;
  int v = (tid < nb) ? bsum[tid] : 0;
  s[tid] = v;
  __syncthreads();
  for (int off = 1; off < 256; off <<= 1) {
    int t = (tid >= off) ? s[tid - off] : 0;
    __syncthreads();
    s[tid] += t;
    __syncthreads();
  }
  if (tid < nb) bsum[tid] = s[tid] - v;
}

__global__ void k_scan_finish(int* __restrict__ rowp, const int* __restrict__ bsum,
                              int* __restrict__ cursor) {
  int i = blockIdx.x * blockDim.x + threadIdx.x;
  if (i < N_NODES) {
    int v = rowp[i] + bsum[i >> 8];
    rowp[i] = v;
    cursor[i] = v;
  }
  if (i == 0) rowp[N_NODES] = N_EDGES;
}

// pack {src:16 | bf16(coef):16} per edge, grouped by dst
__global__ void k_fill_edges(const int* __restrict__ ei, const float* __restrict__ dis,
                             int* __restrict__ cursor, uint* __restrict__ edata) {
  int e = blockIdx.x * blockDim.x + threadIdx.x;
  if (e < N_EDGES) {
    int s = ei[e];
    int d = ei[N_EDGES + e];
    int pos = atomicAdd(&cursor[d], 1);
    edata[pos] = ((uint)s << 16) | f2b(dis[s] * dis[d]);
  }
}

// ---------------- per-layer ----------------

// out16[n][j] = bf16( sum_k bnrelu(in[n][k]) * W[k][j] )
template <bool IN_BF16>
__global__ __launch_bounds__(256) void k_gemm(const void* __restrict__ in,
                                              const float* __restrict__ W,
                                              __hip_bfloat16* __restrict__ out,
                                              float* __restrict__ stats_zero,
                                              const float* __restrict__ stats_in,
                                              const float* __restrict__ gamma,
                                              const float* __restrict__ beta) {
  __shared__ float Al[4][64];
  int tid = threadIdx.x;
  int wid = tid >> 6, f = tid & 63;
  if (blockIdx.x == 0) {
    for (int i = tid; i < 1024; i += 256) stats_zero[i] = 0.0f;
  }
  float Wreg[64];
#pragma unroll
  for (int k = 0; k < 64; ++k) Wreg[k] = W[k * 64 + f];
  float sc = 1.f, sh = 0.f;
  if (stats_in) {
    float s = 0.f, q = 0.f;
#pragma unroll
    for (int c = 0; c < 8; ++c) {
      s += stats_in[c * 128 + f];
      q += stats_in[c * 128 + 64 + f];
    }
    float mu = s * (1.0f / N_NODES);
    float var = q * (1.0f / N_NODES) - mu * mu;
    sc = gamma[f] * rsqrtf(var + BN_EPS);
    sh = beta[f] - mu * sc;
  }
  for (int n = blockIdx.x * 4 + wid; n < N_NODES; n += gridDim.x * 4) {
    float av;
    if (IN_BF16)
      av = __bfloat162float(((const __hip_bfloat16*)in)[(n << 6) + f]);
    else
      av = ((const float*)in)[(n << 6) + f];
    if (stats_in) {
      av = fmaf(av, sc, sh);
      av = av > 0.f ? av : 0.f;
    }
    Al[wid][f] = av;  // same-wave LDS: ordered, no barrier
    float acc = 0.f;
    const float4* arow = (const float4*)Al[wid];
#pragma unroll
    for (int k4 = 0; k4 < 16; ++k4) {
      float4 a = arow[k4];
      acc = fmaf(a.x, Wreg[k4 * 4 + 0], acc);
      acc = fmaf(a.y, Wreg[k4 * 4 + 1], acc);
      acc = fmaf(a.z, Wreg[k4 * 4 + 2], acc);
      acc = fmaf(a.w, Wreg[k4 * 4 + 3], acc);
    }
    out[(n << 6) + f] = __float2bfloat16(acc);
  }
}

// U gather instructions, 8 edges each; edge record pulled from reg via shuffle
template <int U>
__device__ __forceinline__ void gathN(uint er, int jbase, const uint4* __restrict__ hw4,
                                      int l8, int g, float acc[8]) {
  uint e[U];
  uint4 hv[U];
#pragma unroll
  for (int u = 0; u < U; ++u) e[u] = __shfl(er, jbase + u * 8 + g, 64);
#pragma unroll
  for (int u = 0; u < U; ++u) hv[u] = hw4[(e[u] >> 16) * 8 + l8];
#pragma unroll
  for (int u = 0; u < U; ++u) {
    float wv = blo(e[u]);
    acc[0] = fmaf(blo(hv[u].x), wv, acc[0]);
    acc[1] = fmaf(bhi(hv[u].x), wv, acc[1]);
    acc[2] = fmaf(blo(hv[u].y), wv, acc[2]);
    acc[3] = fmaf(bhi(hv[u].y), wv, acc[3]);
    acc[4] = fmaf(blo(hv[u].z), wv, acc[4]);
    acc[5] = fmaf(bhi(hv[u].z), wv, acc[5]);
    acc[6] = fmaf(blo(hv[u].w), wv, acc[6]);
    acc[7] = fmaf(bhi(hv[u].w), wv, acc[7]);
  }
}

__device__ __forceinline__ void do_batch(uint er, int c, const uint4* __restrict__ hw4,
                                         int l8, int g, float acc[8]) {
  if (c > 32) {
    gathN<4>(er, 0, hw4, l8, g, acc);
    gathN<4>(er, 32, hw4, l8, g, acc);
  } else if (c > 16) {
    gathN<4>(er, 0, hw4, l8, g, acc);
  } else if (c > 8) {
    gathN<2>(er, 0, hw4, l8, g, acc);
  } else {
    gathN<1>(er, 0, hw4, l8, g, acc);
  }
}

// gather-aggregate + self-loop + bias; bf16 rows (128B); reg-shuffled edges.
// __launch_bounds__(256,4): 64-VGPR cap (occupancy cliff) WITHOUT spilling.
__global__ __launch_bounds__(256, 4) void k_agg(const __hip_bfloat16* __restrict__ hW,
                                                const float* __restrict__ dis,
                                                const int* __restrict__ rowp,
                                                const uint* __restrict__ edata,
                                                const float* __restrict__ bias,
                                                __hip_bfloat16* __restrict__ act,
                                                float* __restrict__ stats) {
  __shared__ float ssum[4][64], ssq[4][64];
  int tid = threadIdx.x;
  int wid = tid >> 6, lane = tid & 63;
  int g = lane >> 3, l8 = lane & 7;
  ssum[wid][lane] = 0.f;  // same-wave init; only this wave RMWs its slice
  ssq[wid][lane] = 0.f;
  const uint4* hw4 = (const uint4*)hW;
  int stride = gridDim.x * 4;
  int n = blockIdx.x * 4 + wid;
  int p0 = 0, p1 = 0;
  uint er = 0;
  if (n < N_NODES) {
    p0 = rowp[n];
    p1 = rowp[n + 1];
    er = (p0 + lane < p1) ? edata[p0 + lane] : 0u;
  }
  for (; n < N_NODES;) {
    uint4 hself = hw4[n * 8 + l8];  // early, independent
    float dn = dis[n];
    // 1-deep prefetch of next node's rowp + edge block
    int nn = n + stride;
    int q0 = 0, q1 = 0;
    if (nn < N_NODES) {
      q0 = rowp[nn];
      q1 = rowp[nn + 1];
    }
    uint ner = (nn < N_NODES && q0 + lane < q1) ? edata[q0 + lane] : 0u;

    float acc[8] = {0, 0, 0, 0, 0, 0, 0, 0};
    int cnt = p1 - p0;
    do_batch(er, cnt > 64 ? 64 : cnt, hw4, l8, g, acc);
    for (int pb = p0 + 64; pb < p1; pb += 64) {  // rare (deg > 64)
      uint er2 = (pb + lane < p1) ? edata[pb + lane] : 0u;
      int c = p1 - pb;
      do_batch(er2, c > 64 ? 64 : c, hw4, l8, g, acc);
    }
#pragma unroll
    for (int off = 8; off < 64; off <<= 1) {
#pragma unroll
      for (int i = 0; i < 8; ++i) acc[i] += __shfl_xor(acc[i], off, 64);
    }
    if (g == 0) {
      float dn2 = dn * dn;
      float pre[8];
      pre[0] = fmaf(blo(hself.x), dn2, acc[0]);
      pre[1] = fmaf(bhi(hself.x), dn2, acc[1]);
      pre[2] = fmaf(blo(hself.y), dn2, acc[2]);
      pre[3] = fmaf(bhi(hself.y), dn2, acc[3]);
      pre[4] = fmaf(blo(hself.z), dn2, acc[4]);
      pre[5] = fmaf(bhi(hself.z), dn2, acc[5]);
      pre[6] = fmaf(blo(hself.w), dn2, acc[6]);
      pre[7] = fmaf(bhi(hself.w), dn2, acc[7]);
      const float4* b4 = (const float4*)bias;
      float4 bA = b4[l8 * 2], bB = b4[l8 * 2 + 1];
      pre[0] += bA.x; pre[1] += bA.y; pre[2] += bA.z; pre[3] += bA.w;
      pre[4] += bB.x; pre[5] += bB.y; pre[6] += bB.z; pre[7] += bB.w;
      uint4 st;
      st.x = (uint)f2b(pre[0]) | ((uint)f2b(pre[1]) << 16);
      st.y = (uint)f2b(pre[2]) | ((uint)f2b(pre[3]) << 16);
      st.z = (uint)f2b(pre[4]) | ((uint)f2b(pre[5]) << 16);
      st.w = (uint)f2b(pre[6]) | ((uint)f2b(pre[7]) << 16);
      ((uint4*)act)[n * 8 + l8] = st;
      float* su = &ssum[wid][l8 * 8];
      float* sq = &ssq[wid][l8 * 8];
#pragma unroll
      for (int i = 0; i < 8; ++i) {  // LDS RMW: stats never live in regs
        su[i] += pre[i];
        sq[i] = fmaf(pre[i], pre[i], sq[i]);
      }
    }
    n = nn; p0 = q0; p1 = q1; er = ner;
  }
  __syncthreads();
  if (tid < 64) {
    float s4 = ssum[0][tid] + ssum[1][tid] + ssum[2][tid] + ssum[3][tid];
    float q4 = ssq[0][tid] + ssq[1][tid] + ssq[2][tid] + ssq[3][tid];
    float* sl = stats + (blockIdx.x & 7) * 128;  // 8-way de-contended
    atomicAdd(&sl[tid], s4);
    atomicAdd(&sl[64 + tid], q4);
  }
}

// ---------------- pool + MLP ----------------

__global__ __launch_bounds__(256) void k_pool(const __hip_bfloat16* __restrict__ act,
                                              const float* __restrict__ stats_in,
                                              const float* __restrict__ gamma,
                                              const float* __restrict__ beta,
                                              float* __restrict__ pooled) {
  int g = blockIdx.x;
  int tid = threadIdx.x;
  int l16 = tid & 15;   // feats 4*l16 .. 4*l16+3
  int r = tid >> 4;     // 16 row-slices
  float sc[4], sh[4];
#pragma unroll
  for (int i = 0; i < 4; ++i) {
    int f = l16 * 4 + i;
    float s = 0.f, q = 0.f;
#pragma unroll
    for (int c = 0; c < 8; ++c) {
      s += stats_in[c * 128 + f];
      q += stats_in[c * 128 + 64 + f];
    }
    float mu = s * (1.0f / N_NODES);
    float var = q * (1.0f / N_NODES) - mu * mu;
    sc[i] = gamma[f] * rsqrtf(var + BN_EPS);
    sh[i] = beta[f] - mu * sc[i];
  }
  int gs = g * N_NODES;
  int start = (gs + 63) >> 6;
  int end = (gs + N_NODES + 63) >> 6;
  float m[4] = {0.f, 0.f, 0.f, 0.f};  // post-ReLU >= 0
  const uint2* a2 = (const uint2*)act;
  for (int n = start + r; n < end; n += 16) {
    uint2 v = a2[n * 16 + l16];
    float a0 = blo(v.x), a1 = bhi(v.x), a2v = blo(v.y), a3 = bhi(v.y);
    m[0] = fmaxf(m[0], fmaf(a0, sc[0], sh[0]));
    m[1] = fmaxf(m[1], fmaf(a1, sc[1], sh[1]));
    m[2] = fmaxf(m[2], fmaf(a2v, sc[2], sh[2]));
    m[3] = fmaxf(m[3], fmaf(a3, sc[3], sh[3]));
  }
  __shared__ float sm[16][64];
#pragma unroll
  for (int i = 0; i < 4; ++i) sm[r][l16 * 4 + i] = m[i];
  __syncthreads();
  if (tid < 64) {
    float mm = sm[0][tid];
#pragma unroll
    for (int rr = 1; rr < 16; ++rr) mm = fmaxf(mm, sm[rr][tid]);
    pooled[g * 64 + tid] = mm;
  }
}

__global__ __launch_bounds__(256) void k_final(const float* __restrict__ pooled,
                                               const float* __restrict__ w1,
                                               const float* __restrict__ b1,
                                               const float* __restrict__ w2,
                                               const float* __restrict__ b2,
                                               float* __restrict__ out) {
  __shared__ float P[64 * 64];
  __shared__ float Hd[64 * 64];
  int tid = threadIdx.x;
  for (int i = tid; i < 4096; i += 256) P[i] = pooled[i];
  __syncthreads();
  for (int i = tid; i < 4096; i += 256) {
    int g = i >> 6, j = i & 63;
    float acc = b1[j];
#pragma unroll
    for (int k = 0; k < 64; ++k) acc = fmaf(P[g * 64 + k], w1[k * 64 + j], acc);
    Hd[i] = acc > 0.f ? acc : 0.f;
  }
  __syncthreads();
  for (int i = tid; i < 640; i += 256) {
    int g = i / 10, c = i % 10;
    float acc = b2[c];
#pragma unroll
    for (int k = 0; k < 64; ++k) acc = fmaf(Hd[g * 64 + k], w2[k * 10 + c], acc);
    out[i] = acc;
  }
}

// ---------------- launch ----------------

extern "C" void kernel_launch(void* const* d_in, const int* in_sizes, int n_in,
                              void* d_out, int out_size, void* d_ws, size_t ws_size,
                              hipStream_t stream) {
  const float* x = (const float*)d_in[0];
  const int* ei = (const int*)d_in[1];
  const float* W1 = (const float*)d_in[3];
  const float* b1 = (const float*)d_in[4];
  const float* W2 = (const float*)d_in[5];
  const float* b2 = (const float*)d_in[6];
  const float* W3 = (const float*)d_in[7];
  const float* b3 = (const float*)d_in[8];
  const float* gamma = (const float*)d_in[9];
  const float* beta = (const float*)d_in[10];
  const float* l1w = (const float*)d_in[11];
  const float* l1b = (const float*)d_in[12];
  const float* l2w = (const float*)d_in[13];
  const float* l2b = (const float*)d_in[14];
  float* out = (float*)d_out;

  char* ws = (char*)d_ws;
  size_t off = 0;
  auto alloc = [&](size_t bytes) {
    void* p = ws + off;
    off = (off + bytes + 255) & ~(size_t)255;
    return p;
  };
  int* deg = (int*)alloc(N_NODES * 4);
  int* rowp = (int*)alloc((N_NODES + 1) * 4);
  int* cursor = (int*)alloc(N_NODES * 4);
  int* bsum = (int*)alloc(256 * 4);
  uint* edata = (uint*)alloc((size_t)N_EDGES * 4);
  float* dis = (float*)alloc(N_NODES * 4);
  __hip_bfloat16* hW = (__hip_bfloat16*)alloc((size_t)N_NODES * 64 * 2);
  __hip_bfloat16* act = (__hip_bfloat16*)alloc((size_t)N_NODES * 64 * 2);
  float* statsL0 = (float*)alloc(1024 * 4);
  float* statsL1 = (float*)alloc(1024 * 4);
  float* statsL2 = (float*)alloc(1024 * 4);
  float* pooled = (float*)alloc(4096 * 4);

  int nsb = (N_NODES + 255) / 256;  // 196

  hipMemsetAsync(deg, 0, N_NODES * 4, stream);
  k_count_deg<<<(N_EDGES + 255) / 256, 256, 0, stream>>>(ei + N_EDGES, deg);
  k_scan_block<<<nsb, 256, 0, stream>>>(deg, rowp, bsum, dis);
  k_scan_partials<<<1, 256, 0, stream>>>(bsum, nsb);
  k_scan_finish<<<nsb, 256, 0, stream>>>(rowp, bsum, cursor);
  k_fill_edges<<<(N_EDGES + 255) / 256, 256, 0, stream>>>(ei, dis, cursor, edata);

  // layer 1
  k_gemm<false><<<2048, 256, 0, stream>>>(x, W1, hW, statsL0, nullptr, gamma, beta);
  k_agg<<<2048, 256, 0, stream>>>(hW, dis, rowp, edata, b1, act, statsL0);
  // layer 2
  k_gemm<true><<<2048, 256, 0, stream>>>(act, W2, hW, statsL1, statsL0, gamma, beta);
  k_agg<<<2048, 256, 0, stream>>>(hW, dis, rowp, edata, b2, act, statsL1);
  // layer 3
  k_gemm<true><<<2048, 256, 0, stream>>>(act, W3, hW, statsL2, statsL1, gamma, beta);
  k_agg<<<2048, 256, 0, stream>>>(hW, dis, rowp, edata, b3, act, statsL2);

  k_pool<<<N_GRAPHS, 256, 0, stream>>>(act, statsL2, gamma, beta, pooled);
  k_final<<<1, 256, 0, stream>>>(pooled, l1w, l1b, l2w, l2b, out);
}